// Round 1
// baseline (88.667 us; speedup 1.0000x reference)
//
#include <hip/hip_runtime.h>

typedef __bf16  bf16x8 __attribute__((ext_vector_type(8)));
typedef short   s16x8  __attribute__((ext_vector_type(8)));
typedef float   f32x4  __attribute__((ext_vector_type(4)));
typedef unsigned short u16;
typedef u16     u16x4  __attribute__((ext_vector_type(4)));

#define B_SZ 4096
#define D_SZ 256

static constexpr float SCALE = (float)(1.4426950408889634 / 0.07); // log2(e)/T
static constexpr float LN2F  = 0.69314718055994531f;

__device__ __forceinline__ u16 f2bf(float f) {
  unsigned u = __float_as_uint(f);
  unsigned r = u + 0x7FFFu + ((u >> 16) & 1u);   // round-nearest-even
  return (u16)(r >> 16);
}

template<bool BF>
__device__ __forceinline__ bf16x8 ld8(const u16* pb, const float* pf) {
  if constexpr (BF) {
    return *(const bf16x8*)pb;
  } else {
    f32x4 a = *(const f32x4*)pf;
    f32x4 b = *(const f32x4*)(pf + 4);
    s16x8 s;
#pragma unroll
    for (int i = 0; i < 4; ++i) { s[i] = (short)f2bf(a[i]); s[i + 4] = (short)f2bf(b[i]); }
    return __builtin_bit_cast(bf16x8, s);
  }
}

__global__ __launch_bounds__(256) void cl_convert(const float* __restrict__ x,
                                                  const float* __restrict__ y,
                                                  u16* __restrict__ xb,
                                                  u16* __restrict__ yb) {
  const int idx = (int)(blockIdx.x * 256 + threadIdx.x) * 4;
  f32x4 vx = *(const f32x4*)(x + idx);
  f32x4 vy = *(const f32x4*)(y + idx);
  u16x4 sx, sy;
#pragma unroll
  for (int i = 0; i < 4; ++i) { sx[i] = f2bf(vx[i]); sy[i] = f2bf(vy[i]); }
  *(u16x4*)(xb + idx) = sx;
  *(u16x4*)(yb + idx) = sy;
}

// One block = 16 rows of S, all 4096 columns, 64 col-tiles of 64.
// 4 waves; wave w computes cols [16w,16w+16) of each tile via mfma 16x16x32.
// Scan phase: wave w owns rows 4w..4w+3; 16 lanes per row (4 cols each).
template<bool BF>
__global__ __launch_bounds__(256) void cl_main(const float* __restrict__ x,
                                               const float* __restrict__ y,
                                               const u16* __restrict__ xb,
                                               const u16* __restrict__ yb,
                                               float* __restrict__ partials) {
  __shared__ float st[16][68];   // padded: no bank conflicts
  __shared__ float red[256];
  const int tid  = threadIdx.x;
  const int lane = tid & 63;
  const int wv   = tid >> 6;
  const int l15  = lane & 15;
  const int lg   = lane >> 4;          // k-group for frags / row-group for scan
  const int i0   = blockIdx.x * 16;

  // A fragments: row = i0 + (lane&15), k = ks*32 + (lane>>4)*8 .. +7
  bf16x8 A[8];
  {
    const size_t base = (size_t)(i0 + l15) * D_SZ + (lg << 3);
#pragma unroll
    for (int ks = 0; ks < 8; ++ks)
      A[ks] = ld8<BF>(xb + base + ks * 32, x + base + ks * 32);
  }

  float lacc = 0.f;   // log2-domain accumulator (logs + diag term)
  float carry = 0.f;  // running cumsum of exp for this thread's row

  auto load_b = [&](bf16x8 (&F)[8], int t) {
    const size_t jb = (size_t)(t * 64 + (wv << 4) + l15) * D_SZ + (lg << 3);
#pragma unroll
    for (int ks = 0; ks < 8; ++ks)
      F[ks] = ld8<BF>(yb + jb + ks * 32, y + jb + ks * 32);
  };

  auto body = [&](bf16x8 (&F)[8], int t) {
    f32x4 acc = {0.f, 0.f, 0.f, 0.f};
#pragma unroll
    for (int ks = 0; ks < 8; ++ks)
      acc = __builtin_amdgcn_mfma_f32_16x16x32_bf16(A[ks], F[ks], acc, 0, 0, 0);
    __syncthreads();                         // scan(t-1) finished reading st
    const int colg = t * 64 + (wv << 4) + l15;
#pragma unroll
    for (int v = 0; v < 4; ++v) {
      float tv = acc[v] * SCALE;             // t = (x.y)/T * log2(e)
      const int rowl = (lg << 2) + v;        // D row = (lane>>4)*4 + reg
      if (i0 + rowl == colg)                 // diagonal: -(B-i)*S_ii, log2 dom.
        lacc -= (float)(B_SZ - colg) * tv;
      st[rowl][(wv << 4) + l15] = tv;
    }
    __syncthreads();                         // st ready
    // --- scan + log phase ---
    const int row = (wv << 2) + lg;
    f32x4 tv4 = *(const f32x4*)&st[row][l15 << 2];
    float e0 = __builtin_amdgcn_exp2f(tv4[0]);
    float e1 = __builtin_amdgcn_exp2f(tv4[1]);
    float e2 = __builtin_amdgcn_exp2f(tv4[2]);
    float e3 = __builtin_amdgcn_exp2f(tv4[3]);
    float p1 = e0 + e1, p2 = p1 + e2, p3 = p2 + e3;
    float s = p3;
#pragma unroll
    for (int d = 1; d < 16; d <<= 1) {       // inclusive scan over 16 lanes
      float u = __shfl_up(s, (unsigned)d, 16);
      if (l15 >= d) s += u;
    }
    const float base = carry + (s - p3);     // exclusive prefix + carry-in
    const float c0 = (float)(B_SZ - 1 - (t * 64 + (l15 << 2)));
    lacc += __builtin_amdgcn_logf(base + e0 + c0)
          + __builtin_amdgcn_logf(base + p1 + (c0 - 1.f))
          + __builtin_amdgcn_logf(base + p2 + (c0 - 2.f))
          + __builtin_amdgcn_logf(base + p3 + (c0 - 3.f));
    carry += __shfl(s, 15, 16);              // tile total
  };

  // ping-pong double buffer, static indexing only
  bf16x8 B0[8], B1[8];
  load_b(B0, 0);
#pragma unroll 1
  for (int t2 = 0; t2 < 32; ++t2) {
    const int t0 = t2 * 2;
    load_b(B1, t0 + 1);
    body(B0, t0);
    if (t0 + 2 < 64) load_b(B0, t0 + 2);
    body(B1, t0 + 1);
  }

  red[tid] = lacc * LN2F;
  __syncthreads();
#pragma unroll
  for (int off = 128; off > 0; off >>= 1) {
    if (tid < off) red[tid] += red[tid + off];
    __syncthreads();
  }
  if (tid == 0) partials[blockIdx.x] = red[0];
}

__global__ __launch_bounds__(256) void cl_reduce(const float* __restrict__ p,
                                                 float* __restrict__ out) {
  __shared__ float red[256];
  const int tid = threadIdx.x;
  red[tid] = p[tid];
  __syncthreads();
#pragma unroll
  for (int off = 128; off > 0; off >>= 1) {
    if (tid < off) red[tid] += red[tid + off];
    __syncthreads();
  }
  if (tid == 0) out[0] = red[0];
}

extern "C" void kernel_launch(void* const* d_in, const int* in_sizes, int n_in,
                              void* d_out, int out_size, void* d_ws, size_t ws_size,
                              hipStream_t stream) {
  const float* x = (const float*)d_in[0];
  const float* y = (const float*)d_in[1];
  float* out = (float*)d_out;
  float* partials = (float*)d_ws;                 // 256 floats
  const size_t BD = (size_t)B_SZ * D_SZ;
  u16* xb = (u16*)((char*)d_ws + 4096);
  u16* yb = xb + BD;
  const size_t need = 4096 + 4 * BD;              // partials + 2x bf16 copies
  if (ws_size >= need) {
    cl_convert<<<(int)(BD / 1024), 256, 0, stream>>>(x, y, xb, yb);
    cl_main<true><<<B_SZ / 16, 256, 0, stream>>>(x, y, xb, yb, partials);
  } else {
    cl_main<false><<<B_SZ / 16, 256, 0, stream>>>(x, y, xb, yb, partials);
  }
  cl_reduce<<<1, 256, 0, stream>>>(partials, out);
}

// Round 2
// 37.835 us; speedup vs baseline: 2.3435x; 2.3435x over previous
//
#include <hip/hip_runtime.h>

typedef __bf16  bf16x8 __attribute__((ext_vector_type(8)));
typedef short   s16x8  __attribute__((ext_vector_type(8)));
typedef float   f32x4  __attribute__((ext_vector_type(4)));
typedef unsigned short u16;
typedef u16     u16x4  __attribute__((ext_vector_type(4)));
typedef unsigned int u32;

#define B_SZ 4096
#define D_SZ 256

static constexpr float SCALE = (float)(1.4426950408889634 / 0.07); // log2(e)/T
static constexpr float LN2F  = 0.69314718055994531f;

__device__ __forceinline__ u16 f2bf(float f) {
  unsigned u = __float_as_uint(f);
  unsigned r = u + 0x7FFFu + ((u >> 16) & 1u);   // round-nearest-even
  return (u16)(r >> 16);
}
__device__ __forceinline__ float bf2f(u16 h) {
  return __uint_as_float((u32)h << 16);
}

template<bool BF>
__device__ __forceinline__ bf16x8 ld8(const u16* pb, const float* pf) {
  if constexpr (BF) {
    return *(const bf16x8*)pb;
  } else {
    f32x4 a = *(const f32x4*)pf;
    f32x4 b = *(const f32x4*)(pf + 4);
    s16x8 s;
#pragma unroll
    for (int i = 0; i < 4; ++i) { s[i] = (short)f2bf(a[i]); s[i + 4] = (short)f2bf(b[i]); }
    return __builtin_bit_cast(bf16x8, s);
  }
}

__global__ __launch_bounds__(256) void cl_convert(const float* __restrict__ x,
                                                  const float* __restrict__ y,
                                                  u16* __restrict__ xb,
                                                  u16* __restrict__ yb) {
  const int idx = (int)(blockIdx.x * 256 + threadIdx.x) * 4;
  f32x4 vx = *(const f32x4*)(x + idx);
  f32x4 vy = *(const f32x4*)(y + idx);
  u16x4 sx, sy;
#pragma unroll
  for (int i = 0; i < 4; ++i) { sx[i] = f2bf(vx[i]); sy[i] = f2bf(vy[i]); }
  *(u16x4*)(xb + idx) = sx;
  *(u16x4*)(yb + idx) = sy;
}

// ---------------- Phase 1: GEMM  S_log2[i][j] = (x_i . y_j) * log2(e)/T ----
// 128x128 tile, BK=64, 4 waves (2x2 of 64x64), global_load_lds w/ pre-swizzled
// source, XOR-swizzled ds_read (2-way max conflict).
__global__ __launch_bounds__(256, 2) void cl_gemm(const u16* __restrict__ xb,
                                                  const u16* __restrict__ yb,
                                                  u16* __restrict__ Sl) {
  __shared__ u16 As[2][128 * 64];
  __shared__ u16 Bs[2][128 * 64];
  const int tid  = threadIdx.x;
  const int lane = tid & 63;
  const int wv   = tid >> 6;
  const int l15  = lane & 15;
  const int lg   = lane >> 4;
  const int wm   = wv >> 1;        // 0..1
  const int wn   = wv & 1;         // 0..1
  int bid = (int)blockIdx.x;
  bid = (bid & 7) * 128 + (bid >> 3);      // XCD swizzle (1024 % 8 == 0)
  const int brow = (bid >> 5) << 7;
  const int bcol = (bid & 31) << 7;

  auto stage_panel = [&](u16* panel, const u16* src, int row0, int kt) {
#pragma unroll
    for (int i = 0; i < 4; ++i) {
      const int chunk = i * 4 + wv;                 // 0..15 (1 KB each)
      const int r = chunk * 8 + (lane >> 3);        // 0..127
      const int cs = ((lane & 7) << 4) ^ ((r & 7) << 4);   // pre-swizzled src col
      const char* g = (const char*)src + ((size_t)(row0 + r) << 9) + (kt << 7) + cs;
      auto lp = (__attribute__((address_space(3))) u32*)
                  ((char*)panel + chunk * 1024 + lane * 16);
      __builtin_amdgcn_global_load_lds((const __attribute__((address_space(1))) u32*)g,
                                       lp, 16, 0, 0);
    }
  };

  f32x4 acc[4][4] = {};

  stage_panel(As[0], xb, brow, 0);
  stage_panel(Bs[0], yb, bcol, 0);
  __syncthreads();

#pragma unroll 1
  for (int kt = 0; kt < 4; ++kt) {
    if (kt < 3) {
      stage_panel(As[(kt + 1) & 1], xb, brow, kt + 1);
      stage_panel(Bs[(kt + 1) & 1], yb, bcol, kt + 1);
    }
    const u16* Ap = As[kt & 1];
    const u16* Bp = Bs[kt & 1];
    bf16x8 Af[4][2], Bf[4][2];
#pragma unroll
    for (int mi = 0; mi < 4; ++mi)
#pragma unroll
      for (int ks = 0; ks < 2; ++ks) {
        const int ra = (wm << 6) + (mi << 4) + l15;
        const int ca = ((ks << 6) + (lg << 4)) ^ ((ra & 7) << 4);
        Af[mi][ks] = *(const bf16x8*)((const char*)Ap + (ra << 7) + ca);
        const int rb = (wn << 6) + (mi << 4) + l15;
        const int cb = ((ks << 6) + (lg << 4)) ^ ((rb & 7) << 4);
        Bf[mi][ks] = *(const bf16x8*)((const char*)Bp + (rb << 7) + cb);
      }
#pragma unroll
    for (int mi = 0; mi < 4; ++mi)
#pragma unroll
      for (int ni = 0; ni < 4; ++ni)
#pragma unroll
        for (int ks = 0; ks < 2; ++ks)
          acc[mi][ni] = __builtin_amdgcn_mfma_f32_16x16x32_bf16(
              Af[mi][ks], Bf[ni][ks], acc[mi][ni], 0, 0, 0);
    __syncthreads();
  }

  // C-write: row from A's l15-dim -> (lane>>4)*4+v ; col from B's l15
#pragma unroll
  for (int mi = 0; mi < 4; ++mi)
#pragma unroll
    for (int ni = 0; ni < 4; ++ni) {
      const int rg = brow + (wm << 6) + (mi << 4) + (lg << 2);
      const int cg = bcol + (wn << 6) + (ni << 4) + l15;
#pragma unroll
      for (int v = 0; v < 4; ++v)
        Sl[(size_t)(rg + v) * B_SZ + cg] = f2bf(acc[mi][ni][v] * SCALE);
    }
}

// ---------------- Phase 2: per-row cumsum + logs ---------------------------
__global__ __launch_bounds__(256) void cl_scan(const u16* __restrict__ Sl,
                                               float* __restrict__ partials) {
  __shared__ float wtot[4];
  __shared__ float red[256];
  const int row  = (int)blockIdx.x;
  const int tid  = threadIdx.x;
  const int lane = tid & 63;
  const int wv   = tid >> 6;

  const u16* rp = Sl + (size_t)row * B_SZ + tid * 16;
  s16x8 a = *(const s16x8*)rp;
  s16x8 b = *(const s16x8*)(rp + 8);
  float t[16], p[16];
  float run = 0.f;
#pragma unroll
  for (int j = 0; j < 8; ++j) { t[j] = bf2f((u16)a[j]); t[8 + j] = bf2f((u16)b[j]); }
#pragma unroll
  for (int j = 0; j < 16; ++j) { run += __builtin_amdgcn_exp2f(t[j]); p[j] = run; }

  float s = run;
#pragma unroll
  for (int d = 1; d < 64; d <<= 1) {
    float u = __shfl_up(s, (unsigned)d, 64);
    if (lane >= d) s += u;
  }
  if (lane == 63) wtot[wv] = s;
  __syncthreads();
  float off = 0.f;
#pragma unroll
  for (int w = 0; w < 4; ++w) if (w < wv) off += wtot[w];
  const float excl = off + (s - run);

  float lacc = 0.f;
  const int c0 = tid * 16;
#pragma unroll
  for (int j = 0; j < 16; ++j)
    lacc += __builtin_amdgcn_logf(excl + p[j] + (float)(B_SZ - 1 - (c0 + j)));
  if ((row >> 4) == tid) lacc -= (float)(B_SZ - row) * t[row & 15];
  lacc *= LN2F;

  red[tid] = lacc;
  __syncthreads();
#pragma unroll
  for (int o = 128; o > 0; o >>= 1) {
    if (tid < o) red[tid] += red[tid + o];
    __syncthreads();
  }
  if (tid == 0) partials[row] = red[0];
}

__global__ __launch_bounds__(256) void cl_final(const float* __restrict__ p,
                                                float* __restrict__ out) {
  __shared__ float red[256];
  const int tid = threadIdx.x;
  float s = 0.f;
#pragma unroll
  for (int k = 0; k < 16; ++k) s += p[tid + 256 * k];
  red[tid] = s;
  __syncthreads();
#pragma unroll
  for (int o = 128; o > 0; o >>= 1) {
    if (tid < o) red[tid] += red[tid + o];
    __syncthreads();
  }
  if (tid == 0) out[0] = red[0];
}

// ---------------- Fallback (R1 fused kernel, known-good) -------------------
template<bool BF>
__global__ __launch_bounds__(256) void cl_main(const float* __restrict__ x,
                                               const float* __restrict__ y,
                                               const u16* __restrict__ xb,
                                               const u16* __restrict__ yb,
                                               float* __restrict__ partials) {
  __shared__ float st[16][68];
  __shared__ float red[256];
  const int tid  = threadIdx.x;
  const int lane = tid & 63;
  const int wv   = tid >> 6;
  const int l15  = lane & 15;
  const int lg   = lane >> 4;
  const int i0   = blockIdx.x * 16;

  bf16x8 A[8];
  {
    const size_t base = (size_t)(i0 + l15) * D_SZ + (lg << 3);
#pragma unroll
    for (int ks = 0; ks < 8; ++ks)
      A[ks] = ld8<BF>(xb + base + ks * 32, x + base + ks * 32);
  }

  float lacc = 0.f, carry = 0.f;

  auto load_b = [&](bf16x8 (&F)[8], int t) {
    const size_t jb = (size_t)(t * 64 + (wv << 4) + l15) * D_SZ + (lg << 3);
#pragma unroll
    for (int ks = 0; ks < 8; ++ks)
      F[ks] = ld8<BF>(yb + jb + ks * 32, y + jb + ks * 32);
  };

  auto body = [&](bf16x8 (&F)[8], int t) {
    f32x4 acc = {0.f, 0.f, 0.f, 0.f};
#pragma unroll
    for (int ks = 0; ks < 8; ++ks)
      acc = __builtin_amdgcn_mfma_f32_16x16x32_bf16(A[ks], F[ks], acc, 0, 0, 0);
    __syncthreads();
    const int colg = t * 64 + (wv << 4) + l15;
#pragma unroll
    for (int v = 0; v < 4; ++v) {
      float tv = acc[v] * SCALE;
      const int rowl = (lg << 2) + v;
      if (i0 + rowl == colg) lacc -= (float)(B_SZ - colg) * tv;
      st[rowl][(wv << 4) + l15] = tv;
    }
    __syncthreads();
    const int row = (wv << 2) + lg;
    f32x4 tv4 = *(const f32x4*)&st[row][l15 << 2];
    float e0 = __builtin_amdgcn_exp2f(tv4[0]);
    float e1 = __builtin_amdgcn_exp2f(tv4[1]);
    float e2 = __builtin_amdgcn_exp2f(tv4[2]);
    float e3 = __builtin_amdgcn_exp2f(tv4[3]);
    float p1 = e0 + e1, p2 = p1 + e2, p3 = p2 + e3;
    float s = p3;
#pragma unroll
    for (int d = 1; d < 16; d <<= 1) {
      float u = __shfl_up(s, (unsigned)d, 16);
      if (l15 >= d) s += u;
    }
    const float base = carry + (s - p3);
    const float c0 = (float)(B_SZ - 1 - (t * 64 + (l15 << 2)));
    lacc += __builtin_amdgcn_logf(base + e0 + c0)
          + __builtin_amdgcn_logf(base + p1 + (c0 - 1.f))
          + __builtin_amdgcn_logf(base + p2 + (c0 - 2.f))
          + __builtin_amdgcn_logf(base + p3 + (c0 - 3.f));
    carry += __shfl(s, 15, 16);
  };

  bf16x8 B0[8], B1[8];
  load_b(B0, 0);
#pragma unroll 1
  for (int t2 = 0; t2 < 32; ++t2) {
    const int t0 = t2 * 2;
    load_b(B1, t0 + 1);
    body(B0, t0);
    if (t0 + 2 < 64) load_b(B0, t0 + 2);
    body(B1, t0 + 1);
  }

  red[tid] = lacc * LN2F;
  __syncthreads();
#pragma unroll
  for (int o = 128; o > 0; o >>= 1) {
    if (tid < o) red[tid] += red[tid + o];
    __syncthreads();
  }
  if (tid == 0) partials[blockIdx.x] = red[0];
}

__global__ __launch_bounds__(256) void cl_reduce(const float* __restrict__ p,
                                                 float* __restrict__ out) {
  __shared__ float red[256];
  const int tid = threadIdx.x;
  red[tid] = p[tid];
  __syncthreads();
#pragma unroll
  for (int o = 128; o > 0; o >>= 1) {
    if (tid < o) red[tid] += red[tid + o];
    __syncthreads();
  }
  if (tid == 0) out[0] = red[0];
}

extern "C" void kernel_launch(void* const* d_in, const int* in_sizes, int n_in,
                              void* d_out, int out_size, void* d_ws, size_t ws_size,
                              hipStream_t stream) {
  const float* x = (const float*)d_in[0];
  const float* y = (const float*)d_in[1];
  float* out = (float*)d_out;
  const size_t BD = (size_t)B_SZ * D_SZ;

  // New-path layout: partials(16KB) | xb(2MB) | yb(2MB) | Sl(32MB)
  float* partials = (float*)d_ws;
  u16* xb = (u16*)((char*)d_ws + 16384);
  u16* yb = xb + BD;
  u16* Sl = yb + BD;
  const size_t need = 16384 + 4 * BD + 2 * (size_t)B_SZ * B_SZ;

  if (ws_size >= need) {
    cl_convert<<<(int)(BD / 1024), 256, 0, stream>>>(x, y, xb, yb);
    cl_gemm<<<1024, 256, 0, stream>>>(xb, yb, Sl);
    cl_scan<<<B_SZ, 256, 0, stream>>>(Sl, partials);
    cl_final<<<1, 256, 0, stream>>>(partials, out);
  } else {
    // Fallback: R1 fused path (original layout: partials@0, xb@4KB)
    float* fpart = (float*)d_ws;
    u16* fxb = (u16*)((char*)d_ws + 4096);
    u16* fyb = fxb + BD;
    const size_t fneed = 4096 + 4 * BD;
    if (ws_size >= fneed) {
      cl_convert<<<(int)(BD / 1024), 256, 0, stream>>>(x, y, fxb, fyb);
      cl_main<true><<<B_SZ / 16, 256, 0, stream>>>(x, y, fxb, fyb, fpart);
    } else {
      cl_main<false><<<B_SZ / 16, 256, 0, stream>>>(x, y, fxb, fyb, fpart);
    }
    cl_reduce<<<1, 256, 0, stream>>>(fpart, out);
  }
}